// Round 4
// baseline (620.572 us; speedup 1.0000x reference)
//
#include <hip/hip_runtime.h>
#include <hip/hip_bf16.h>
#include <stdint.h>

#define NP 409600
#define HG 640
#define WG 640
#define HW (HG*WG)
// spatial tiles: 16x16 cells, ~50% density => ~128 points/tile = one conv block
#define TPB  40          // tiles per axis (640/16)
#define NTILE 3200       // 2 * 40 * 40

typedef __bf16 bf16x8 __attribute__((ext_vector_type(8)));
typedef float f32x4 __attribute__((ext_vector_type(4)));

// ---------------- prep kernels ----------------

// counting sort by spatial tile: hist -> exclusive scan -> scatter order
__global__ void hist_kernel(const int* __restrict__ coords, int* __restrict__ hist) {
    int i = blockIdx.x * 256 + threadIdx.x;
    int b = coords[3*i], y = coords[3*i+1], x = coords[3*i+2];
    atomicAdd(&hist[b*(TPB*TPB) + (y>>4)*TPB + (x>>4)], 1);
}

__global__ void scan_kernel(int* __restrict__ hist) {   // 1 block, 256 threads, 13 vals each
    __shared__ int part[256];
    int t = threadIdx.x;
    int loc[13];
    int s = 0;
    #pragma unroll
    for (int k = 0; k < 13; ++k) {
        int idx = t*13 + k;
        int v = (idx < NTILE) ? hist[idx] : 0;
        loc[k] = s; s += v;
    }
    part[t] = s;
    __syncthreads();
    for (int off = 1; off < 256; off <<= 1) {   // Hillis-Steele inclusive scan
        int v = (t >= off) ? part[t - off] : 0;
        __syncthreads();
        part[t] += v;
        __syncthreads();
    }
    int pre = (t > 0) ? part[t-1] : 0;
    #pragma unroll
    for (int k = 0; k < 13; ++k) {
        int idx = t*13 + k;
        if (idx < NTILE) hist[idx] = pre + loc[k];
    }
}

// ord[pos] = original id; lsort[pos] = packed coord; grid[lin] = sorted pos (fused)
__global__ void ord_kernel(const int* __restrict__ coords, int* __restrict__ offs,
                           int* __restrict__ ord, int* __restrict__ lsort,
                           int* __restrict__ grid) {
    int i = blockIdx.x * 256 + threadIdx.x;
    int b = coords[3*i], y = coords[3*i+1], x = coords[3*i+2];
    int tile = b*(TPB*TPB) + (y>>4)*TPB + (x>>4);
    int pos = atomicAdd(&offs[tile], 1);
    int lin = b*HW + y*WG + x;
    ord[pos]   = i;
    lsort[pos] = lin;
    grid[lin]  = pos;
}

// permute + cast: fpermb[j] = bf16(features[ord[j]]); 8 threads per row
__global__ void perm_cast_kernel(const float* __restrict__ f, const int* __restrict__ ord,
                                 __hip_bfloat16* __restrict__ fpermb) {
    int t = blockIdx.x * 256 + threadIdx.x;       // grid = 12800 blocks
    int j = t >> 3, part = t & 7;
    int i = ord[j];
    const float4* p = (const float4*)(f + (long)i*64 + part*8);
    float4 a = p[0], b = p[1];
    union { uint4 q; __hip_bfloat16 h[8]; } u;
    u.h[0] = __float2bfloat16(a.x); u.h[1] = __float2bfloat16(a.y);
    u.h[2] = __float2bfloat16(a.z); u.h[3] = __float2bfloat16(a.w);
    u.h[4] = __float2bfloat16(b.x); u.h[5] = __float2bfloat16(b.y);
    u.h[6] = __float2bfloat16(b.z); u.h[7] = __float2bfloat16(b.w);
    *(uint4*)(fpermb + (long)j*64 + part*8) = u.q;
}

// neighbor table over SORTED order j; center tap (tt==4) omitted (always self).
// values are SORTED positions (index fpermb / y1 directly)
__global__ void nbr_kernel(const int* __restrict__ lsort, const int* __restrict__ grid,
                           int* __restrict__ nbrp) {
    int j = blockIdx.x * 256 + threadIdx.x;
    int lin = lsort[j];
    int b = lin / HW;
    int rem = lin - b*HW;
    int y = rem / WG;
    int x = rem - y*WG;
    int baseg = b*HW;
    #pragma unroll
    for (int tt = 0; tt < 9; ++tt) {
        if (tt == 4) continue;
        int ti = tt < 4 ? tt : tt - 1;
        int ny = y + tt/3 - 1, nx = x + tt%3 - 1;
        int g = -1;
        if (ny >= 0 && ny < HG && nx >= 0 && nx < WG)
            g = grid[baseg + ny*WG + nx];
        nbrp[ti*NP + j] = g;
    }
}

// weights pre-cast to bf16 and transposed to [tap][n=out_ch][k=in_ch]
__global__ void cast_w_kernel(const float* __restrict__ w1, const float* __restrict__ w2,
                              const float* __restrict__ wd,
                              __hip_bfloat16* __restrict__ wc1, __hip_bfloat16* __restrict__ wc2) {
    int i = blockIdx.x * 256 + threadIdx.x;   // grid = 77824 threads exactly
    if (i < 9*4096) {
        int t = i >> 12, r = i & 4095, n = r >> 6, k = r & 63;
        wc1[i] = __float2bfloat16(w1[(t << 12) + (k << 6) + n]);
    }
    int j = i - 9*4096;
    if (j >= 0 && j < 10*4096) {
        int t = j >> 12, r = j & 4095, n = r >> 6, k = r & 63;
        float v = (t < 9) ? w2[(t << 12) + (k << 6) + n] : wd[(k << 6) + n];
        wc2[j] = __float2bfloat16(v);
    }
}

// ---------------- LDS-free gather-GEMM conv kernel ----------------
// 128 sorted rows x 64 cols per block, 4 waves; wave w owns rows [w*32, w*32+32).
// Each lane loads its MFMA fragments DIRECTLY from global:
//   A: lane l -> row g(wave*32 + (l&15)) (+16 for a1), bytes [(l>>4)*8 + ks*32]*2
//   B: lane l -> wT[t][c*16 + (l&15)][(l>>4)*8 + ks*32]   (L1-resident, shared)
// No LDS, no __syncthreads, no bank conflicts; taps pipeline freely.
// FINAL: tap 9 = identity(fpermb, contiguous rows) @ wd into short-lived accR
// (reference applies relu(conv2+b2) BEFORE adding the residual).

template<bool FINAL>
__launch_bounds__(256)
__global__ void conv_kernel(const __hip_bfloat16* __restrict__ src,    // sorted-order gather source
                            const __hip_bfloat16* __restrict__ idsrc,  // identity source (FINAL)
                            const int* __restrict__ nbrp,              // [8][NP] sorted positions
                            const int* __restrict__ ord,               // sorted pos -> orig id
                            const __hip_bfloat16* __restrict__ wT,     // [NTAP][64][64] (n,k)
                            const float* __restrict__ bias,
                            __hip_bfloat16* __restrict__ out_bf,       // sorted order (conv1)
                            float* __restrict__ out_f) {               // original order (conv2)
    const int tid = threadIdx.x;
    // XCD-aware swizzle: 3200 blocks, 8 XCDs, 400 contiguous spatial tiles per XCD
    const int sbid = (blockIdx.x & 7) * 400 + (blockIdx.x >> 3);
    const int base = sbid * 128;
    const int wave = tid >> 6, lane = tid & 63;
    const int mrow = lane & 15;          // fragment row / B col
    const int kq   = lane >> 4;          // k-quad
    const int r0 = base + wave*32 + mrow;
    const int r1 = r0 + 16;

    union { uint4 q; bf16x8 v; } uz; uz.q = make_uint4(0u,0u,0u,0u);
    const bf16x8 Z = uz.v;

    auto ldA = [&](const __hip_bfloat16* p, int g, int kb) -> bf16x8 {
        union { uint4 q; bf16x8 v; } u;
        u.q = *(const uint4*)(p + (long)g*64 + kb);
        return u.v;
    };

    f32x4 acc[2][4];
    #pragma unroll
    for (int i = 0; i < 2; ++i)
        #pragma unroll
        for (int j = 0; j < 4; ++j)
            acc[i][j] = (f32x4){0.f, 0.f, 0.f, 0.f};

    int g0 = nbrp[r0];          // tap 0 (tt=0 -> ti=0)
    int g1 = nbrp[r1];

    #pragma unroll
    for (int t = 0; t < 9; ++t) {
        const __hip_bfloat16* wp = wT + t*4096;
        const int kb0 = kq*8, kb1 = 32 + kq*8;
        bf16x8 a00 = (g0 >= 0) ? ldA(src, g0, kb0) : Z;
        bf16x8 a01 = (g0 >= 0) ? ldA(src, g0, kb1) : Z;
        bf16x8 a10 = (g1 >= 0) ? ldA(src, g1, kb0) : Z;
        bf16x8 a11 = (g1 >= 0) ? ldA(src, g1, kb1) : Z;
        // prefetch next tap's neighbor indices (2 VGPRs)
        if (t + 1 < 9) {
            int tn = t + 1;
            if (tn == 4) { g0 = r0; g1 = r1; }
            else {
                int ti = tn < 4 ? tn : tn - 1;
                g0 = nbrp[ti*NP + r0];
                g1 = nbrp[ti*NP + r1];
            }
        }
        #pragma unroll
        for (int ks = 0; ks < 2; ++ks) {
            int kb = ks*32 + kq*8;
            bf16x8 b0 = *(const bf16x8*)(wp + ( 0 + mrow)*64 + kb);
            bf16x8 b1 = *(const bf16x8*)(wp + (16 + mrow)*64 + kb);
            bf16x8 b2 = *(const bf16x8*)(wp + (32 + mrow)*64 + kb);
            bf16x8 b3 = *(const bf16x8*)(wp + (48 + mrow)*64 + kb);
            bf16x8 a0 = ks ? a01 : a00;
            bf16x8 a1 = ks ? a11 : a10;
            acc[0][0] = __builtin_amdgcn_mfma_f32_16x16x32_bf16(a0, b0, acc[0][0], 0, 0, 0);
            acc[0][1] = __builtin_amdgcn_mfma_f32_16x16x32_bf16(a0, b1, acc[0][1], 0, 0, 0);
            acc[0][2] = __builtin_amdgcn_mfma_f32_16x16x32_bf16(a0, b2, acc[0][2], 0, 0, 0);
            acc[0][3] = __builtin_amdgcn_mfma_f32_16x16x32_bf16(a0, b3, acc[0][3], 0, 0, 0);
            acc[1][0] = __builtin_amdgcn_mfma_f32_16x16x32_bf16(a1, b0, acc[1][0], 0, 0, 0);
            acc[1][1] = __builtin_amdgcn_mfma_f32_16x16x32_bf16(a1, b1, acc[1][1], 0, 0, 0);
            acc[1][2] = __builtin_amdgcn_mfma_f32_16x16x32_bf16(a1, b2, acc[1][2], 0, 0, 0);
            acc[1][3] = __builtin_amdgcn_mfma_f32_16x16x32_bf16(a1, b3, acc[1][3], 0, 0, 0);
        }
    }

    const int col = mrow, quad = kq;

    if (FINAL) {
        // residual tap: contiguous identity rows @ wd, short-lived accumulator
        f32x4 accR[2][4];
        #pragma unroll
        for (int i = 0; i < 2; ++i)
            #pragma unroll
            for (int j = 0; j < 4; ++j)
                accR[i][j] = (f32x4){0.f, 0.f, 0.f, 0.f};
        const __hip_bfloat16* wp = wT + 9*4096;
        #pragma unroll
        for (int ks = 0; ks < 2; ++ks) {
            int kb = ks*32 + kq*8;
            bf16x8 a0 = ldA(idsrc, r0, kb);
            bf16x8 a1 = ldA(idsrc, r1, kb);
            bf16x8 b0 = *(const bf16x8*)(wp + ( 0 + mrow)*64 + kb);
            bf16x8 b1 = *(const bf16x8*)(wp + (16 + mrow)*64 + kb);
            bf16x8 b2 = *(const bf16x8*)(wp + (32 + mrow)*64 + kb);
            bf16x8 b3 = *(const bf16x8*)(wp + (48 + mrow)*64 + kb);
            accR[0][0] = __builtin_amdgcn_mfma_f32_16x16x32_bf16(a0, b0, accR[0][0], 0, 0, 0);
            accR[0][1] = __builtin_amdgcn_mfma_f32_16x16x32_bf16(a0, b1, accR[0][1], 0, 0, 0);
            accR[0][2] = __builtin_amdgcn_mfma_f32_16x16x32_bf16(a0, b2, accR[0][2], 0, 0, 0);
            accR[0][3] = __builtin_amdgcn_mfma_f32_16x16x32_bf16(a0, b3, accR[0][3], 0, 0, 0);
            accR[1][0] = __builtin_amdgcn_mfma_f32_16x16x32_bf16(a1, b0, accR[1][0], 0, 0, 0);
            accR[1][1] = __builtin_amdgcn_mfma_f32_16x16x32_bf16(a1, b1, accR[1][1], 0, 0, 0);
            accR[1][2] = __builtin_amdgcn_mfma_f32_16x16x32_bf16(a1, b2, accR[1][2], 0, 0, 0);
            accR[1][3] = __builtin_amdgcn_mfma_f32_16x16x32_bf16(a1, b3, accR[1][3], 0, 0, 0);
        }
        #pragma unroll
        for (int cb = 0; cb < 4; ++cb) {
            float bv = bias[cb*16 + col];
            #pragma unroll
            for (int mb = 0; mb < 2; ++mb) {
                #pragma unroll
                for (int r = 0; r < 4; ++r) {
                    float v = acc[mb][cb][r] + bv;
                    v = v > 0.f ? v : 0.f;
                    v += accR[mb][cb][r];      // residual added AFTER inner relu
                    v = v > 0.f ? v : 0.f;
                    int srt = base + wave*32 + mb*16 + quad*4 + r;
                    long row = ord[srt];       // scatter to original order
                    out_f[row*64 + cb*16 + col] = v;
                }
            }
        }
    } else {
        #pragma unroll
        for (int cb = 0; cb < 4; ++cb) {
            float bv = bias[cb*16 + col];
            #pragma unroll
            for (int mb = 0; mb < 2; ++mb) {
                #pragma unroll
                for (int r = 0; r < 4; ++r) {
                    float v = acc[mb][cb][r] + bv;
                    v = v > 0.f ? v : 0.f;
                    int srt = base + wave*32 + mb*16 + quad*4 + r;
                    out_bf[(long)srt*64 + cb*16 + col] = __float2bfloat16(v);   // stay sorted
                }
            }
        }
    }
}

// ---------------- launch ----------------

extern "C" void kernel_launch(void* const* d_in, const int* in_sizes, int n_in,
                              void* d_out, int out_size, void* d_ws, size_t ws_size,
                              hipStream_t stream) {
    const float* features = (const float*)d_in[0];
    const int*   coords   = (const int*)d_in[1];
    const float* w1 = (const float*)d_in[2];
    const float* b1 = (const float*)d_in[3];
    const float* w2 = (const float*)d_in[4];
    const float* b2 = (const float*)d_in[5];
    const float* wd = (const float*)d_in[6];
    float* out = (float*)d_out;

    char* ws = (char*)d_ws;
    int*            grid   = (int*)ws;                           //  3,276,800 B
    int*            nbrp   = (int*)(ws + 3276800);               // 13,107,200 B (8 taps)
    int*            ord    = (int*)(ws + 16384000);              //  1,638,400 B
    __hip_bfloat16* fpermb = (__hip_bfloat16*)(ws + 18022400);   // 52,428,800 B
    __hip_bfloat16* y1     = (__hip_bfloat16*)(ws + 70451200);   // 52,428,800 B
    __hip_bfloat16* wc1    = (__hip_bfloat16*)(ws + 122880000);  //     73,728 B
    __hip_bfloat16* wc2    = (__hip_bfloat16*)(ws + 122953728);  //     81,920 B
    // total 123,035,648 B
    // lsort + hist live in y1's region (dead until conv1 writes y1)
    int* lsort = (int*)(ws + 70451200);                          //  1,638,400 B
    int* hist  = (int*)(ws + 70451200 + 1638400);                //     12,800 B

    hipMemsetAsync(grid, 0xFF, (size_t)HW * 2 * sizeof(int), stream);   // grid = -1
    hipMemsetAsync(hist, 0x00, (size_t)NTILE * sizeof(int), stream);

    hist_kernel     <<<1600,  256, 0, stream>>>(coords, hist);
    scan_kernel     <<<1,     256, 0, stream>>>(hist);
    ord_kernel      <<<1600,  256, 0, stream>>>(coords, hist, ord, lsort, grid);
    cast_w_kernel   <<<304,   256, 0, stream>>>(w1, w2, wd, wc1, wc2);
    nbr_kernel      <<<1600,  256, 0, stream>>>(lsort, grid, nbrp);
    perm_cast_kernel<<<12800, 256, 0, stream>>>(features, ord, fpermb);

    conv_kernel<false><<<3200, 256, 0, stream>>>(fpermb, nullptr, nbrp, ord, wc1, b1, y1, nullptr);
    conv_kernel<true ><<<3200, 256, 0, stream>>>(y1, fpermb, nbrp, ord, wc2, b2, nullptr, out);
}